// Round 2
// baseline (14077.722 us; speedup 1.0000x reference)
//
#include <hip/hip_runtime.h>
#include <stdint.h>

#define T_STEPS 2048
#define HID 1024
#define G4 4096
#define NWG 64

typedef __attribute__((ext_vector_type(8))) short short8;
typedef __attribute__((ext_vector_type(4))) float float4v;
typedef __attribute__((ext_vector_type(4))) unsigned int uint4v;
typedef unsigned long long ull;

// ---------- ws layout ----------
// [0, 131072)              : h double buffer (2 x 64KB), FRAGMENT-ordered:
//                            byte(s,r,c2) = s*2048 + r*64 + c2  (s=K-slice 0..31,
//                            r=batch 0..31, c2 = 2*(col - 32s) in [0,64))
// [131072, 132096)         : flags (256 u32 = NWG x 4 waves), global-step monotonic
// [132608, 132612)         : dtype flag (1 = bf16 inputs, 0 = fp32 inputs)
// [135168, 266240)         : c state fp32 [32][1024] (persists across chunks)
// [0x100000, +TC*262144)   : x_proj bf16 chunk, [t_local][g][b]
#define HBUF_OFF 0ull
#define FLAG_OFF 131072ull
#define DT_OFF   132608ull
#define CST_OFF  135168ull
#define XP_OFF   0x100000ull

__device__ inline unsigned short f2bf(float f) {
  union { float f; unsigned int u; } v; v.f = f;
  unsigned int u = v.u;
  return (unsigned short)((u + 0x7fffu + ((u >> 16) & 1u)) >> 16);
}
__device__ inline float bf2f(unsigned short h) {
  union { unsigned int u; float f; } v; v.u = ((unsigned int)h) << 16;
  return v.f;
}
__device__ inline short8 pack8(float4 a, float4 b) {
  short8 r;
  r[0] = (short)f2bf(a.x); r[1] = (short)f2bf(a.y);
  r[2] = (short)f2bf(a.z); r[3] = (short)f2bf(a.w);
  r[4] = (short)f2bf(b.x); r[5] = (short)f2bf(b.y);
  r[6] = (short)f2bf(b.z); r[7] = (short)f2bf(b.w);
  return r;
}

// =====================================================================
// Dtype sniffer (unchanged)
// =====================================================================
__global__ void dtype_sniff(const unsigned short* __restrict__ w,
                            unsigned int* __restrict__ dt) {
  __shared__ int red[256];
  const int tid = threadIdx.x;
  int cnt = 0;
#pragma unroll
  for (int i = 0; i < 4; i++) {
    unsigned short h = w[tid * 4 + i];
    unsigned e = (h >> 7) & 0xFF;
    if (h == 0 || (e >= 100 && e <= 123)) cnt++;
  }
  red[tid] = cnt;
  __syncthreads();
  for (int s = 128; s > 0; s >>= 1) {
    if (tid < s) red[tid] += red[tid + s];
    __syncthreads();
  }
  if (tid == 0) dt[0] = (red[0] >= 922) ? 1u : 0u;   // 90% of 1024
}

// =====================================================================
// Phase A (unchanged): x_proj[tl][g][b] = x[b][t0+tl][:] . W_ih[g][:] + bias
// =====================================================================
__global__ __launch_bounds__(256) void xproj_gemm(
    const void* __restrict__ x, const void* __restrict__ Wih,
    const void* __restrict__ bih, const void* __restrict__ bhh,
    unsigned short* __restrict__ xp, int t0,
    const unsigned int* __restrict__ dt)
{
  __shared__ char smem[32768];
  __shared__ float bias_s[128];
  unsigned short* As = (unsigned short*)smem;            // [128][40]
  unsigned short* Bs = (unsigned short*)(smem + 10240);

  const bool isbf = (*dt != 0);

  const int bid = blockIdx.x;
  const int panel = bid >> 9;
  const int within = bid & 511;
  const int nt = within & 31;
  const int mt = (panel << 4) + (within >> 5);
  const int m0 = mt * 128;
  const int n0 = nt * 128;
  const int tl0 = m0 >> 5;

  const int tid = threadIdx.x;
  if (tid < 128) {
    bias_s[tid] = isbf
        ? bf2f(((const unsigned short*)bih)[n0 + tid]) +
          bf2f(((const unsigned short*)bhh)[n0 + tid])
        : ((const float*)bih)[n0 + tid] + ((const float*)bhh)[n0 + tid];
  }

  const int w = tid >> 6, lane = tid & 63;
  const int quad = lane >> 4, lr = lane & 15;
  const int wm = (w & 1) * 64, wn = (w >> 1) * 64;

  float4v acc[4][4];
#pragma unroll
  for (int i = 0; i < 4; i++)
#pragma unroll
    for (int j = 0; j < 4; j++) acc[i][j] = (float4v){0.f, 0.f, 0.f, 0.f};

  const int r = tid >> 1, half = tid & 1;
  const size_t aoff =
      ((size_t)(r & 31) * T_STEPS + (size_t)(t0 + tl0 + (r >> 5))) * HID + half * 16;
  const size_t boff = (size_t)(n0 + r) * HID + half * 16;
  unsigned short* adst = As + r * 40 + half * 16;
  unsigned short* bdst = Bs + r * 40 + half * 16;

  for (int k0 = 0; k0 < HID; k0 += 32) {
    __syncthreads();
    if (isbf) {
      const unsigned short* a16 = (const unsigned short*)x + aoff + k0;
      const unsigned short* b16 = (const unsigned short*)Wih + boff + k0;
      *(short8*)(adst)     = *(const short8*)(a16);
      *(short8*)(adst + 8) = *(const short8*)(a16 + 8);
      *(short8*)(bdst)     = *(const short8*)(b16);
      *(short8*)(bdst + 8) = *(const short8*)(b16 + 8);
    } else {
      const float4* af = (const float4*)((const float*)x + aoff + k0);
      const float4* bf = (const float4*)((const float*)Wih + boff + k0);
      float4 a0 = af[0], a1 = af[1], a2 = af[2], a3 = af[3];
      float4 b0 = bf[0], b1 = bf[1], b2 = bf[2], b3 = bf[3];
      *(short8*)(adst)     = pack8(a0, a1);
      *(short8*)(adst + 8) = pack8(a2, a3);
      *(short8*)(bdst)     = pack8(b0, b1);
      *(short8*)(bdst + 8) = pack8(b2, b3);
    }
    __syncthreads();
    short8 afr[4], bfr[4];
#pragma unroll
    for (int i = 0; i < 4; i++)
      afr[i] = *(const short8*)(As + (wm + i * 16 + lr) * 40 + quad * 8);
#pragma unroll
    for (int j = 0; j < 4; j++)
      bfr[j] = *(const short8*)(Bs + (wn + j * 16 + lr) * 40 + quad * 8);
#pragma unroll
    for (int i = 0; i < 4; i++)
#pragma unroll
      for (int j = 0; j < 4; j++)
        acc[i][j] = __builtin_amdgcn_mfma_f32_16x16x32_bf16(afr[i], bfr[j], acc[i][j], 0, 0, 0);
  }

  __syncthreads();
  unsigned short* ep = (unsigned short*)smem;
#pragma unroll
  for (int i = 0; i < 4; i++)
#pragma unroll
    for (int j = 0; j < 4; j++)
#pragma unroll
      for (int rr = 0; rr < 4; rr++) {
        int ml = wm + i * 16 + quad * 4 + rr;
        int nl = wn + j * 16 + lr;
        float v = acc[i][j][rr] + bias_s[nl];
        ep[(((ml >> 5) * 128) + nl) * 32 + (ml & 31)] = f2bf(v);
      }
  __syncthreads();
#pragma unroll
  for (int tl = 0; tl < 4; tl++) {
    const uint4* s4 = (const uint4*)(smem + tl * 8192);
    uint4* d4 = (uint4*)(xp + ((size_t)(tl0 + tl) * G4 + n0) * 32);
    for (int i = tid; i < 512; i += 256) d4[i] = s4[i];
  }
}

// =====================================================================
// Phase R: persistent LSTM recurrence.
// 64 WGs x 256 thr; WG g owns h-cols [16g,16g+16); wave w = gate w.
// hbuf is FRAGMENT-ordered, so:
//  - gather = 16 inline-asm global_load_dwordx4 (sc0 sc1, MALL-coherent)
//    per thread into NAMED regs (forced in-flight) + one vmcnt(0) drain +
//    16 contiguous ds_write_b128 -> ~1 round trip, conflict-free.
//  - GEMM A-fragment ds_read_b128 is contiguous 1KB/instr, conflict-free.
// Cell: thread owns (row b = 8w+(lane>>3), cols 2k,2k+1), publishes its
// own packed 4B (agent-scope) -> per-wave vmcnt drain -> per-wave flag.
// Only 2 barriers per step.
// =====================================================================
__global__ __launch_bounds__(256, 1) void lstm_rec(
    const void* __restrict__ Whh,
    const unsigned short* __restrict__ xp,
    unsigned short* __restrict__ hbuf,   // 2 x 64KB fragment-ordered
    unsigned int* __restrict__ flags,    // NWG*4, global-step monotonic
    float* __restrict__ cstate,          // [32][1024] fp32, persists
    void* __restrict__ out,              // [h(32x1024) ; c(32x1024)]
    int t0, int tc,
    const unsigned int* __restrict__ dt)
{
  __shared__ __align__(16) unsigned short hs[32768];  // 64KB fragment-ordered
  __shared__ float gbuf[64][33];                      // [local gate col][batch]

  const bool isbf = (*dt != 0);
  const int wg = blockIdx.x;
  const int tid = threadIdx.x;
  const int w = tid >> 6, lane = tid & 63;
  const int quad = lane >> 4, lr = lane & 15;

  // --- W_hh B-fragments: wave w = gate w; lane lr = col wg*16+lr ---
  short8 bfrag[32];
  {
    const size_t grow = (size_t)w * HID + wg * 16 + lr;   // global gate row
    if (isbf) {
      const unsigned short* wrow = (const unsigned short*)Whh + grow * HID;
#pragma unroll
      for (int s = 0; s < 32; s++)
        bfrag[s] = *(const short8*)(wrow + s * 32 + quad * 8);
    } else {
      const float* wrow = (const float*)Whh + grow * HID;
#pragma unroll
      for (int s = 0; s < 32; s++) {
        float4 f0 = *(const float4*)(wrow + s * 32 + quad * 8);
        float4 f1 = *(const float4*)(wrow + s * 32 + quad * 8 + 4);
        bfrag[s] = pack8(f0, f1);
      }
    }
  }

  const int b  = 8 * w + (lane >> 3);   // batch row owned in cell
  const int k8 = lane & 7;              // col-pair index
  const int j0 = 2 * k8, j1 = j0 + 1;   // local cols in [0,16)
  const int gc0 = wg * 16 + j0, gc1 = gc0 + 1;
  float cs0 = cstate[(size_t)b * HID + gc0];
  float cs1 = cstate[(size_t)b * HID + gc1];
  long budget = 50000000;

  for (int t = t0; t < t0 + tc; t++) {
    // ---- prefetch xp gate values (issued before the spin) ----
    const unsigned short* xpt = xp + (size_t)(t - t0) * (G4 * 32);
    unsigned short rx0 = xpt[(size_t)gc0 * 32 + b];
    unsigned short rx1 = xpt[(size_t)(HID + gc0) * 32 + b];
    unsigned short rx2 = xpt[(size_t)(2 * HID + gc0) * 32 + b];
    unsigned short rx3 = xpt[(size_t)(3 * HID + gc0) * 32 + b];
    unsigned short rx4 = xpt[(size_t)gc1 * 32 + b];
    unsigned short rx5 = xpt[(size_t)(HID + gc1) * 32 + b];
    unsigned short rx6 = xpt[(size_t)(2 * HID + gc1) * 32 + b];
    unsigned short rx7 = xpt[(size_t)(3 * HID + gc1) * 32 + b];

    // ---- every wave polls: lane l watches WG l's 4 wave-flags ----
    {
      const unsigned target = (unsigned)t;
      const unsigned int* fp = flags + 4 * lane;
      for (;;) {
        unsigned f0 = __hip_atomic_load(fp + 0, __ATOMIC_RELAXED, __HIP_MEMORY_SCOPE_AGENT);
        unsigned f1 = __hip_atomic_load(fp + 1, __ATOMIC_RELAXED, __HIP_MEMORY_SCOPE_AGENT);
        unsigned f2 = __hip_atomic_load(fp + 2, __ATOMIC_RELAXED, __HIP_MEMORY_SCOPE_AGENT);
        unsigned f3 = __hip_atomic_load(fp + 3, __ATOMIC_RELAXED, __HIP_MEMORY_SCOPE_AGENT);
        unsigned m01 = f0 < f1 ? f0 : f1;
        unsigned m23 = f2 < f3 ? f2 : f3;
        unsigned mn  = m01 < m23 ? m01 : m23;
        if (mn >= target) break;
        if (--budget < 0) break;
      }
    }

    // ---- bulk h gather: 16 x 16B/thread, ALL in flight, 1 drain ----
    {
      const uint4v* src = (const uint4v*)(hbuf + (size_t)(t & 1) * 32768) + tid;
      uint4v v0, v1, v2, v3, v4, v5, v6, v7, v8, v9, v10, v11, v12, v13, v14, v15;
#define GL(i, dst) \
      asm volatile("global_load_dwordx4 %0, %1, off sc0 sc1" \
                   : "=v"(dst) : "v"(src + (i) * 256) : "memory")
      GL(0, v0);  GL(1, v1);  GL(2, v2);  GL(3, v3);
      GL(4, v4);  GL(5, v5);  GL(6, v6);  GL(7, v7);
      GL(8, v8);  GL(9, v9);  GL(10, v10); GL(11, v11);
      GL(12, v12); GL(13, v13); GL(14, v14); GL(15, v15);
#undef GL
      asm volatile("s_waitcnt vmcnt(0)" ::: "memory");
      uint4v* d = (uint4v*)hs + tid;
      d[0 * 256]  = v0;  d[1 * 256]  = v1;  d[2 * 256]  = v2;  d[3 * 256]  = v3;
      d[4 * 256]  = v4;  d[5 * 256]  = v5;  d[6 * 256]  = v6;  d[7 * 256]  = v7;
      d[8 * 256]  = v8;  d[9 * 256]  = v9;  d[10 * 256] = v10; d[11 * 256] = v11;
      d[12 * 256] = v12; d[13 * 256] = v13; d[14 * 256] = v14; d[15 * 256] = v15;
    }
    __syncthreads();   // barrier A: hs complete (also protects gbuf, see below)

    // ---- GEMM: fragment-ordered A reads (conflict-free), 4 acc chains ----
    float4v acc00 = (float4v){0.f, 0.f, 0.f, 0.f};
    float4v acc01 = (float4v){0.f, 0.f, 0.f, 0.f};
    float4v acc10 = (float4v){0.f, 0.f, 0.f, 0.f};
    float4v acc11 = (float4v){0.f, 0.f, 0.f, 0.f};
    {
      const char* a0 = (const char*)hs + lr * 64 + quad * 16;  // batches 0..15
      const char* a1 = a0 + 1024;                              // batches 16..31
#pragma unroll
      for (int s = 0; s < 32; s += 2) {
        short8 x00 = *(const short8*)(a0 + (size_t)s * 2048);
        short8 x01 = *(const short8*)(a0 + (size_t)s * 2048 + 2048);
        short8 x10 = *(const short8*)(a1 + (size_t)s * 2048);
        short8 x11 = *(const short8*)(a1 + (size_t)s * 2048 + 2048);
        acc00 = __builtin_amdgcn_mfma_f32_16x16x32_bf16(x00, bfrag[s],     acc00, 0, 0, 0);
        acc01 = __builtin_amdgcn_mfma_f32_16x16x32_bf16(x01, bfrag[s + 1], acc01, 0, 0, 0);
        acc10 = __builtin_amdgcn_mfma_f32_16x16x32_bf16(x10, bfrag[s],     acc10, 0, 0, 0);
        acc11 = __builtin_amdgcn_mfma_f32_16x16x32_bf16(x11, bfrag[s + 1], acc11, 0, 0, 0);
      }
    }
    {
      float4v g0 = acc00 + acc01;   // batches 0..15
      float4v g1 = acc10 + acc11;   // batches 16..31
      const int lc = w * 16 + lr;   // local gate col
#pragma unroll
      for (int rr = 0; rr < 4; rr++) {
        gbuf[lc][quad * 4 + rr]      = g0[rr];
        gbuf[lc][16 + quad * 4 + rr] = g1[rr];
      }
    }
    __syncthreads();   // barrier B: gbuf complete

    // ---- cell + self-publish (no extra barrier) ----
    {
      float gi0 = gbuf[j0][b]      + bf2f(rx0);
      float gf0 = gbuf[16 + j0][b] + bf2f(rx1);
      float gg0 = gbuf[32 + j0][b] + bf2f(rx2);
      float go0 = gbuf[48 + j0][b] + bf2f(rx3);
      float si0 = 1.f / (1.f + __expf(-gi0));
      float sf0 = 1.f / (1.f + __expf(-gf0));
      float tg0 = tanhf(gg0);
      float so0 = 1.f / (1.f + __expf(-go0));
      cs0 = sf0 * cs0 + si0 * tg0;
      float hn0 = so0 * tanhf(cs0);

      float gi1 = gbuf[j1][b]      + bf2f(rx4);
      float gf1 = gbuf[16 + j1][b] + bf2f(rx5);
      float gg1 = gbuf[32 + j1][b] + bf2f(rx6);
      float go1 = gbuf[48 + j1][b] + bf2f(rx7);
      float si1 = 1.f / (1.f + __expf(-gi1));
      float sf1 = 1.f / (1.f + __expf(-gf1));
      float tg1 = tanhf(gg1);
      float so1 = 1.f / (1.f + __expf(-go1));
      cs1 = sf1 * cs1 + si1 * tg1;
      float hn1 = so1 * tanhf(cs1);

      // publish packed (col j0 | col j1) into fragment-ordered hbuf
      unsigned pk = (unsigned)f2bf(hn0) | ((unsigned)f2bf(hn1) << 16);
      unsigned int* hb32 = (unsigned int*)hbuf;
      const unsigned idx = (unsigned)(((t + 1) & 1) * 16384 +
                                      (wg >> 1) * 512 + b * 16 + (wg & 1) * 8 + k8);
      __hip_atomic_store(hb32 + idx, pk, __ATOMIC_RELAXED, __HIP_MEMORY_SCOPE_AGENT);

      if (t == T_STEPS - 1) {
        if (isbf) {
          unsigned short* ob = (unsigned short*)out;
          ob[(size_t)b * HID + gc0] = f2bf(hn0);
          ob[(size_t)b * HID + gc1] = f2bf(hn1);
          ob[32768 + (size_t)b * HID + gc0] = f2bf(cs0);
          ob[32768 + (size_t)b * HID + gc1] = f2bf(cs1);
        } else {
          float* of = (float*)out;
          of[(size_t)b * HID + gc0] = hn0;
          of[(size_t)b * HID + gc1] = hn1;
          of[32768 + (size_t)b * HID + gc0] = cs0;
          of[32768 + (size_t)b * HID + gc1] = cs1;
        }
      }
    }
    // per-wave drain, then per-wave flag release
    asm volatile("s_waitcnt vmcnt(0)" ::: "memory");
    if (lane == 0)
      __hip_atomic_store(&flags[wg * 4 + w], (unsigned)(t + 1), __ATOMIC_RELAXED,
                         __HIP_MEMORY_SCOPE_AGENT);
  }

  // persist c for the next chunk
  cstate[(size_t)b * HID + gc0] = cs0;
  cstate[(size_t)b * HID + gc1] = cs1;
}

extern "C" void kernel_launch(void* const* d_in, const int* in_sizes, int n_in,
                              void* d_out, int out_size, void* d_ws, size_t ws_size,
                              hipStream_t stream) {
  (void)in_sizes; (void)n_in; (void)out_size;
  const void* x   = d_in[0];
  const void* Wih = d_in[1];
  const void* Whh = d_in[2];
  const void* bih = d_in[3];
  const void* bhh = d_in[4];

  char* ws = (char*)d_ws;
  unsigned short* hbuf   = (unsigned short*)(ws + HBUF_OFF);
  unsigned int*   flags  = (unsigned int*)(ws + FLAG_OFF);
  unsigned int*   dt     = (unsigned int*)(ws + DT_OFF);
  float*          cstate = (float*)(ws + CST_OFF);
  unsigned short* xp     = (unsigned short*)(ws + XP_OFF);

  int tc = 2048;
  while (tc > 16 && XP_OFF + (size_t)tc * 262144ull > ws_size) tc >>= 1;

  hipMemsetAsync(ws, 0, CST_OFF + 131072, stream);

  hipLaunchKernelGGL(dtype_sniff, dim3(1), dim3(256), 0, stream,
                     (const unsigned short*)Wih, dt);

  for (int t0 = 0; t0 < T_STEPS; t0 += tc) {
    hipLaunchKernelGGL(xproj_gemm, dim3(tc * 8), dim3(256), 0, stream,
                       x, Wih, bih, bhh, xp, t0, dt);
    hipLaunchKernelGGL(lstm_rec, dim3(NWG), dim3(256), 0, stream,
                       Whh, xp, hbuf, flags, cstate, d_out, t0, tc, dt);
  }
}

// Round 3
// 12782.357 us; speedup vs baseline: 1.1013x; 1.1013x over previous
//
#include <hip/hip_runtime.h>
#include <stdint.h>

#define T_STEPS 2048
#define HID 1024
#define G4 4096
#define NWG 64

typedef __attribute__((ext_vector_type(8))) short short8;
typedef __attribute__((ext_vector_type(4))) float float4v;
typedef __attribute__((ext_vector_type(4))) unsigned int uint4v;
typedef unsigned long long ull;

// ---------- ws layout ----------
// [0, 131072)              : h double buffer (2 x 64KB), WG-contiguous:
//                            u32[parity][wg][batch][8 colpairs]  (1KB per WG)
// [131072, 132096)         : flags (256 u32 = NWG x 4 waves), global-step monotonic
// [132608, 132612)         : dtype flag (1 = bf16 inputs, 0 = fp32 inputs)
// [135168, 266240)         : c state fp32 [32][1024] (persists across chunks)
// [0x100000, +TC*262144)   : x_proj bf16 chunk, [t_local][g][b]
#define HBUF_OFF 0ull
#define FLAG_OFF 131072ull
#define DT_OFF   132608ull
#define CST_OFF  135168ull
#define XP_OFF   0x100000ull

__device__ inline unsigned short f2bf(float f) {
  union { float f; unsigned int u; } v; v.f = f;
  unsigned int u = v.u;
  return (unsigned short)((u + 0x7fffu + ((u >> 16) & 1u)) >> 16);
}
__device__ inline float bf2f(unsigned short h) {
  union { unsigned int u; float f; } v; v.u = ((unsigned int)h) << 16;
  return v.f;
}
__device__ inline short8 pack8(float4 a, float4 b) {
  short8 r;
  r[0] = (short)f2bf(a.x); r[1] = (short)f2bf(a.y);
  r[2] = (short)f2bf(a.z); r[3] = (short)f2bf(a.w);
  r[4] = (short)f2bf(b.x); r[5] = (short)f2bf(b.y);
  r[6] = (short)f2bf(b.z); r[7] = (short)f2bf(b.w);
  return r;
}

// =====================================================================
// Dtype sniffer (unchanged)
// =====================================================================
__global__ void dtype_sniff(const unsigned short* __restrict__ w,
                            unsigned int* __restrict__ dt) {
  __shared__ int red[256];
  const int tid = threadIdx.x;
  int cnt = 0;
#pragma unroll
  for (int i = 0; i < 4; i++) {
    unsigned short h = w[tid * 4 + i];
    unsigned e = (h >> 7) & 0xFF;
    if (h == 0 || (e >= 100 && e <= 123)) cnt++;
  }
  red[tid] = cnt;
  __syncthreads();
  for (int s = 128; s > 0; s >>= 1) {
    if (tid < s) red[tid] += red[tid + s];
    __syncthreads();
  }
  if (tid == 0) dt[0] = (red[0] >= 922) ? 1u : 0u;   // 90% of 1024
}

// =====================================================================
// Phase A (unchanged): x_proj[tl][g][b] = x[b][t0+tl][:] . W_ih[g][:] + bias
// =====================================================================
__global__ __launch_bounds__(256) void xproj_gemm(
    const void* __restrict__ x, const void* __restrict__ Wih,
    const void* __restrict__ bih, const void* __restrict__ bhh,
    unsigned short* __restrict__ xp, int t0,
    const unsigned int* __restrict__ dt)
{
  __shared__ char smem[32768];
  __shared__ float bias_s[128];
  unsigned short* As = (unsigned short*)smem;            // [128][40]
  unsigned short* Bs = (unsigned short*)(smem + 10240);

  const bool isbf = (*dt != 0);

  const int bid = blockIdx.x;
  const int panel = bid >> 9;
  const int within = bid & 511;
  const int nt = within & 31;
  const int mt = (panel << 4) + (within >> 5);
  const int m0 = mt * 128;
  const int n0 = nt * 128;
  const int tl0 = m0 >> 5;

  const int tid = threadIdx.x;
  if (tid < 128) {
    bias_s[tid] = isbf
        ? bf2f(((const unsigned short*)bih)[n0 + tid]) +
          bf2f(((const unsigned short*)bhh)[n0 + tid])
        : ((const float*)bih)[n0 + tid] + ((const float*)bhh)[n0 + tid];
  }

  const int w = tid >> 6, lane = tid & 63;
  const int quad = lane >> 4, lr = lane & 15;
  const int wm = (w & 1) * 64, wn = (w >> 1) * 64;

  float4v acc[4][4];
#pragma unroll
  for (int i = 0; i < 4; i++)
#pragma unroll
    for (int j = 0; j < 4; j++) acc[i][j] = (float4v){0.f, 0.f, 0.f, 0.f};

  const int r = tid >> 1, half = tid & 1;
  const size_t aoff =
      ((size_t)(r & 31) * T_STEPS + (size_t)(t0 + tl0 + (r >> 5))) * HID + half * 16;
  const size_t boff = (size_t)(n0 + r) * HID + half * 16;
  unsigned short* adst = As + r * 40 + half * 16;
  unsigned short* bdst = Bs + r * 40 + half * 16;

  for (int k0 = 0; k0 < HID; k0 += 32) {
    __syncthreads();
    if (isbf) {
      const unsigned short* a16 = (const unsigned short*)x + aoff + k0;
      const unsigned short* b16 = (const unsigned short*)Wih + boff + k0;
      *(short8*)(adst)     = *(const short8*)(a16);
      *(short8*)(adst + 8) = *(const short8*)(a16 + 8);
      *(short8*)(bdst)     = *(const short8*)(b16);
      *(short8*)(bdst + 8) = *(const short8*)(b16 + 8);
    } else {
      const float4* af = (const float4*)((const float*)x + aoff + k0);
      const float4* bf = (const float4*)((const float*)Wih + boff + k0);
      float4 a0 = af[0], a1 = af[1], a2 = af[2], a3 = af[3];
      float4 b0 = bf[0], b1 = bf[1], b2 = bf[2], b3 = bf[3];
      *(short8*)(adst)     = pack8(a0, a1);
      *(short8*)(adst + 8) = pack8(a2, a3);
      *(short8*)(bdst)     = pack8(b0, b1);
      *(short8*)(bdst + 8) = pack8(b2, b3);
    }
    __syncthreads();
    short8 afr[4], bfr[4];
#pragma unroll
    for (int i = 0; i < 4; i++)
      afr[i] = *(const short8*)(As + (wm + i * 16 + lr) * 40 + quad * 8);
#pragma unroll
    for (int j = 0; j < 4; j++)
      bfr[j] = *(const short8*)(Bs + (wn + j * 16 + lr) * 40 + quad * 8);
#pragma unroll
    for (int i = 0; i < 4; i++)
#pragma unroll
      for (int j = 0; j < 4; j++)
        acc[i][j] = __builtin_amdgcn_mfma_f32_16x16x32_bf16(afr[i], bfr[j], acc[i][j], 0, 0, 0);
  }

  __syncthreads();
  unsigned short* ep = (unsigned short*)smem;
#pragma unroll
  for (int i = 0; i < 4; i++)
#pragma unroll
    for (int j = 0; j < 4; j++)
#pragma unroll
      for (int rr = 0; rr < 4; rr++) {
        int ml = wm + i * 16 + quad * 4 + rr;
        int nl = wn + j * 16 + lr;
        float v = acc[i][j][rr] + bias_s[nl];
        ep[(((ml >> 5) * 128) + nl) * 32 + (ml & 31)] = f2bf(v);
      }
  __syncthreads();
#pragma unroll
  for (int tl = 0; tl < 4; tl++) {
    const uint4* s4 = (const uint4*)(smem + tl * 8192);
    uint4* d4 = (uint4*)(xp + ((size_t)(tl0 + tl) * G4 + n0) * 32);
    for (int i = tid; i < 512; i += 256) d4[i] = s4[i];
  }
}

// =====================================================================
// Phase R: persistent LSTM recurrence. 64 WGs x 256 thr.
// hbuf: WG-contiguous u32[parity][wg][b][8 colpairs] -> publish = 256B
// contiguous per wave (full single-owner MALL lines); gather = coalesced
// 1KB wave-loads, 16 in flight (named asm regs), one vmcnt(0) drain.
// hs (LDS) is fragment-ordered WITH XOR swizzle: 16B-slot ^= (b>>1)&3,
// making both the gather ds_write and GEMM ds_read <=2-way (free).
// Poll: wave 0 only, lane l = one dwordx4 over WG l's 4 per-wave flags,
// then barrier. 3 barriers/step total.
// =====================================================================
__global__ __launch_bounds__(256, 1) void lstm_rec(
    const void* __restrict__ Whh,
    const unsigned short* __restrict__ xp,
    unsigned short* __restrict__ hbuf,   // 2 x 64KB WG-contiguous
    unsigned int* __restrict__ flags,    // NWG*4, global-step monotonic
    float* __restrict__ cstate,          // [32][1024] fp32, persists
    void* __restrict__ out,              // [h(32x1024) ; c(32x1024)]
    int t0, int tc,
    const unsigned int* __restrict__ dt)
{
  __shared__ __align__(16) unsigned short hs[32768];  // 64KB fragment-ordered+swz
  __shared__ float gbuf[64][33];                      // [local gate col][batch]

  const bool isbf = (*dt != 0);
  const int wg = blockIdx.x;
  const int tid = threadIdx.x;
  const int w = tid >> 6, lane = tid & 63;
  const int quad = lane >> 4, lr = lane & 15;

  // --- W_hh B-fragments: wave w = gate w; lane lr = col wg*16+lr ---
  short8 bfrag[32];
  {
    const size_t grow = (size_t)w * HID + wg * 16 + lr;   // global gate row
    if (isbf) {
      const unsigned short* wrow = (const unsigned short*)Whh + grow * HID;
#pragma unroll
      for (int s = 0; s < 32; s++)
        bfrag[s] = *(const short8*)(wrow + s * 32 + quad * 8);
    } else {
      const float* wrow = (const float*)Whh + grow * HID;
#pragma unroll
      for (int s = 0; s < 32; s++) {
        float4 f0 = *(const float4*)(wrow + s * 32 + quad * 8);
        float4 f1 = *(const float4*)(wrow + s * 32 + quad * 8 + 4);
        bfrag[s] = pack8(f0, f1);
      }
    }
  }

  // gather geometry: thread's 16 chunks come from wgp = 4i+w, fixed (b,h8)
  const int gb = lane >> 1, gh = lane & 1;          // gather batch, col-half
  const int gc = 2 * w + gh;                        // half-index base (q = 8i+gc)
  const int gslot = (gc & 3) ^ ((gb >> 1) & 3);     // swizzled 16B slot
  char* gdst = (char*)hs + ((gc >> 2) * 2048 + gb * 64 + gslot * 16);

  // GEMM read geometry (swizzle must match)
  const int qsw = quad ^ ((lr >> 1) & 3);
  const char* ga0 = (const char*)hs + lr * 64 + qsw * 16;         // batches 0..15
  const char* ga1 = (const char*)hs + (16 + lr) * 64 + qsw * 16;  // batches 16..31

  // cell ownership: (batch cb, cols 2*ck, 2*ck+1)
  const int cb = 8 * w + (lane >> 3);
  const int ck = lane & 7;
  const int j0 = 2 * ck, j1 = j0 + 1;
  const int gc0 = wg * 16 + j0, gc1 = gc0 + 1;
  float cs0 = cstate[(size_t)cb * HID + gc0];
  float cs1 = cstate[(size_t)cb * HID + gc1];
  long budget = 50000000;

  for (int t = t0; t < t0 + tc; t++) {
    // ---- prefetch xp gate values (issued before the spin) ----
    const unsigned short* xpt = xp + (size_t)(t - t0) * (G4 * 32);
    unsigned short rx0 = xpt[(size_t)gc0 * 32 + cb];
    unsigned short rx1 = xpt[(size_t)(HID + gc0) * 32 + cb];
    unsigned short rx2 = xpt[(size_t)(2 * HID + gc0) * 32 + cb];
    unsigned short rx3 = xpt[(size_t)(3 * HID + gc0) * 32 + cb];
    unsigned short rx4 = xpt[(size_t)gc1 * 32 + cb];
    unsigned short rx5 = xpt[(size_t)(HID + gc1) * 32 + cb];
    unsigned short rx6 = xpt[(size_t)(2 * HID + gc1) * 32 + cb];
    unsigned short rx7 = xpt[(size_t)(3 * HID + gc1) * 32 + cb];

    // ---- wave 0 polls: lane l = WG l's 4 wave-flags (one dwordx4) ----
    if (w == 0) {
      const unsigned target = (unsigned)t;
      const unsigned int* fp = flags + 4 * lane;
      for (;;) {
        uint4v f;
        asm volatile("global_load_dwordx4 %0, %1, off sc0 sc1\n\t"
                     "s_waitcnt vmcnt(0)"
                     : "=v"(f) : "v"(fp) : "memory");
        unsigned m01 = f[0] < f[1] ? f[0] : f[1];
        unsigned m23 = f[2] < f[3] ? f[2] : f[3];
        if ((m01 < m23 ? m01 : m23) >= target) break;
        if (--budget < 0) break;
        __builtin_amdgcn_s_sleep(1);
      }
    }
    __syncthreads();   // barrier D: step-t h is fully published

    // ---- bulk h gather: 16 x 16B/thread, ALL in flight, 1 drain,
    //      swizzled ds_write (<=2-way) ----
    {
      const uint4v* src = (const uint4v*)(hbuf + (size_t)(t & 1) * 32768) + tid;
      uint4v v0, v1, v2, v3, v4, v5, v6, v7, v8, v9, v10, v11, v12, v13, v14, v15;
#define GL(i, dst) \
      asm volatile("global_load_dwordx4 %0, %1, off sc0 sc1" \
                   : "=v"(dst) : "v"(src + (i) * 256) : "memory")
      GL(0, v0);  GL(1, v1);  GL(2, v2);  GL(3, v3);
      GL(4, v4);  GL(5, v5);  GL(6, v6);  GL(7, v7);
      GL(8, v8);  GL(9, v9);  GL(10, v10); GL(11, v11);
      GL(12, v12); GL(13, v13); GL(14, v14); GL(15, v15);
#undef GL
      asm volatile("s_waitcnt vmcnt(0)" ::: "memory");
      *(uint4v*)(gdst + 0 * 4096)  = v0;  *(uint4v*)(gdst + 1 * 4096)  = v1;
      *(uint4v*)(gdst + 2 * 4096)  = v2;  *(uint4v*)(gdst + 3 * 4096)  = v3;
      *(uint4v*)(gdst + 4 * 4096)  = v4;  *(uint4v*)(gdst + 5 * 4096)  = v5;
      *(uint4v*)(gdst + 6 * 4096)  = v6;  *(uint4v*)(gdst + 7 * 4096)  = v7;
      *(uint4v*)(gdst + 8 * 4096)  = v8;  *(uint4v*)(gdst + 9 * 4096)  = v9;
      *(uint4v*)(gdst + 10 * 4096) = v10; *(uint4v*)(gdst + 11 * 4096) = v11;
      *(uint4v*)(gdst + 12 * 4096) = v12; *(uint4v*)(gdst + 13 * 4096) = v13;
      *(uint4v*)(gdst + 14 * 4096) = v14; *(uint4v*)(gdst + 15 * 4096) = v15;
    }
    __syncthreads();   // barrier A: hs complete

    // ---- GEMM: swizzled fragment reads (<=2-way), 4 acc chains ----
    float4v acc00 = (float4v){0.f, 0.f, 0.f, 0.f};
    float4v acc01 = (float4v){0.f, 0.f, 0.f, 0.f};
    float4v acc10 = (float4v){0.f, 0.f, 0.f, 0.f};
    float4v acc11 = (float4v){0.f, 0.f, 0.f, 0.f};
#pragma unroll
    for (int s = 0; s < 32; s += 2) {
      short8 x00 = *(const short8*)(ga0 + (size_t)s * 2048);
      short8 x01 = *(const short8*)(ga0 + (size_t)s * 2048 + 2048);
      short8 x10 = *(const short8*)(ga1 + (size_t)s * 2048);
      short8 x11 = *(const short8*)(ga1 + (size_t)s * 2048 + 2048);
      acc00 = __builtin_amdgcn_mfma_f32_16x16x32_bf16(x00, bfrag[s],     acc00, 0, 0, 0);
      acc01 = __builtin_amdgcn_mfma_f32_16x16x32_bf16(x01, bfrag[s + 1], acc01, 0, 0, 0);
      acc10 = __builtin_amdgcn_mfma_f32_16x16x32_bf16(x10, bfrag[s],     acc10, 0, 0, 0);
      acc11 = __builtin_amdgcn_mfma_f32_16x16x32_bf16(x11, bfrag[s + 1], acc11, 0, 0, 0);
    }
    {
      float4v g0 = acc00 + acc01;   // batches 0..15
      float4v g1 = acc10 + acc11;   // batches 16..31
      const int lc = w * 16 + lr;   // local gate col
#pragma unroll
      for (int rr = 0; rr < 4; rr++) {
        gbuf[lc][quad * 4 + rr]      = g0[rr];
        gbuf[lc][16 + quad * 4 + rr] = g1[rr];
      }
    }
    __syncthreads();   // barrier B: gbuf complete

    // ---- cell + self-publish (contiguous per wave; no extra barrier) ----
    {
      float gi0 = gbuf[j0][cb]      + bf2f(rx0);
      float gf0 = gbuf[16 + j0][cb] + bf2f(rx1);
      float gg0 = gbuf[32 + j0][cb] + bf2f(rx2);
      float go0 = gbuf[48 + j0][cb] + bf2f(rx3);
      float si0 = 1.f / (1.f + __expf(-gi0));
      float sf0 = 1.f / (1.f + __expf(-gf0));
      float tg0 = tanhf(gg0);
      float so0 = 1.f / (1.f + __expf(-go0));
      cs0 = sf0 * cs0 + si0 * tg0;
      float hn0 = so0 * tanhf(cs0);

      float gi1 = gbuf[j1][cb]      + bf2f(rx4);
      float gf1 = gbuf[16 + j1][cb] + bf2f(rx5);
      float gg1 = gbuf[32 + j1][cb] + bf2f(rx6);
      float go1 = gbuf[48 + j1][cb] + bf2f(rx7);
      float si1 = 1.f / (1.f + __expf(-gi1));
      float sf1 = 1.f / (1.f + __expf(-gf1));
      float tg1 = tanhf(gg1);
      float so1 = 1.f / (1.f + __expf(-go1));
      cs1 = sf1 * cs1 + si1 * tg1;
      float hn1 = so1 * tanhf(cs1);

      // publish packed (col j0 | col j1): u32 idx = wg*256 + 64w + lane
      unsigned pk = (unsigned)f2bf(hn0) | ((unsigned)f2bf(hn1) << 16);
      unsigned int* hb32 = (unsigned int*)hbuf;
      const unsigned idx = (unsigned)(((t + 1) & 1) * 16384 +
                                      wg * 256 + cb * 8 + ck);
      __hip_atomic_store(hb32 + idx, pk, __ATOMIC_RELAXED, __HIP_MEMORY_SCOPE_AGENT);

      if (t == T_STEPS - 1) {
        if (isbf) {
          unsigned short* ob = (unsigned short*)out;
          ob[(size_t)cb * HID + gc0] = f2bf(hn0);
          ob[(size_t)cb * HID + gc1] = f2bf(hn1);
          ob[32768 + (size_t)cb * HID + gc0] = f2bf(cs0);
          ob[32768 + (size_t)cb * HID + gc1] = f2bf(cs1);
        } else {
          float* of = (float*)out;
          of[(size_t)cb * HID + gc0] = hn0;
          of[(size_t)cb * HID + gc1] = hn1;
          of[32768 + (size_t)cb * HID + gc0] = cs0;
          of[32768 + (size_t)cb * HID + gc1] = cs1;
        }
      }
    }
    // per-wave drain, then per-wave flag release
    asm volatile("s_waitcnt vmcnt(0)" ::: "memory");
    if (lane == 0)
      __hip_atomic_store(&flags[wg * 4 + w], (unsigned)(t + 1), __ATOMIC_RELAXED,
                         __HIP_MEMORY_SCOPE_AGENT);
  }

  // persist c for the next chunk
  cstate[(size_t)cb * HID + gc0] = cs0;
  cstate[(size_t)cb * HID + gc1] = cs1;
}

extern "C" void kernel_launch(void* const* d_in, const int* in_sizes, int n_in,
                              void* d_out, int out_size, void* d_ws, size_t ws_size,
                              hipStream_t stream) {
  (void)in_sizes; (void)n_in; (void)out_size;
  const void* x   = d_in[0];
  const void* Wih = d_in[1];
  const void* Whh = d_in[2];
  const void* bih = d_in[3];
  const void* bhh = d_in[4];

  char* ws = (char*)d_ws;
  unsigned short* hbuf   = (unsigned short*)(ws + HBUF_OFF);
  unsigned int*   flags  = (unsigned int*)(ws + FLAG_OFF);
  unsigned int*   dt     = (unsigned int*)(ws + DT_OFF);
  float*          cstate = (float*)(ws + CST_OFF);
  unsigned short* xp     = (unsigned short*)(ws + XP_OFF);

  int tc = 2048;
  while (tc > 16 && XP_OFF + (size_t)tc * 262144ull > ws_size) tc >>= 1;

  hipMemsetAsync(ws, 0, CST_OFF + 131072, stream);

  hipLaunchKernelGGL(dtype_sniff, dim3(1), dim3(256), 0, stream,
                     (const unsigned short*)Wih, dt);

  for (int t0 = 0; t0 < T_STEPS; t0 += tc) {
    hipLaunchKernelGGL(xproj_gemm, dim3(tc * 8), dim3(256), 0, stream,
                       x, Wih, bih, bhh, xp, t0, dt);
    hipLaunchKernelGGL(lstm_rec, dim3(NWG), dim3(256), 0, stream,
                       Whh, xp, hbuf, flags, cstate, d_out, t0, tc, dt);
  }
}

// Round 4
// 11115.059 us; speedup vs baseline: 1.2665x; 1.1500x over previous
//
#include <hip/hip_runtime.h>
#include <stdint.h>

#define T_STEPS 2048
#define HID 1024
#define G4 4096
#define NWG 64

typedef __attribute__((ext_vector_type(8))) short short8;
typedef __attribute__((ext_vector_type(4))) float float4v;
typedef __attribute__((ext_vector_type(4))) unsigned int uint4v;
typedef unsigned long long ull;

// ---------- ws layout ----------
// [0, 131072)              : h double buffer (2 x 64KB), WG-contiguous:
//                            byte = parity*65536 + wg*1024 + b*32 + c'*2
//                            (b = batch 0..31, c' = col-within-wg 0..15)
// [131072, 132096)         : flags (256 u32 = NWG x 4 waves), global-step monotonic
// [132608, 132612)         : dtype flag (1 = bf16 inputs, 0 = fp32 inputs)
// [135168, 266240)         : c state fp32 [32][1024] (persists across chunks)
// [0x100000, +TC*262144)   : x_proj bf16 chunk, [t_local][g][b]
#define HBUF_OFF 0ull
#define FLAG_OFF 131072ull
#define DT_OFF   132608ull
#define CST_OFF  135168ull
#define XP_OFF   0x100000ull

__device__ inline unsigned short f2bf(float f) {
  union { float f; unsigned int u; } v; v.f = f;
  unsigned int u = v.u;
  return (unsigned short)((u + 0x7fffu + ((u >> 16) & 1u)) >> 16);
}
__device__ inline float bf2f(unsigned short h) {
  union { unsigned int u; float f; } v; v.u = ((unsigned int)h) << 16;
  return v.f;
}
__device__ inline short8 pack8(float4 a, float4 b) {
  short8 r;
  r[0] = (short)f2bf(a.x); r[1] = (short)f2bf(a.y);
  r[2] = (short)f2bf(a.z); r[3] = (short)f2bf(a.w);
  r[4] = (short)f2bf(b.x); r[5] = (short)f2bf(b.y);
  r[6] = (short)f2bf(b.z); r[7] = (short)f2bf(b.w);
  return r;
}

// =====================================================================
// Dtype sniffer (unchanged)
// =====================================================================
__global__ void dtype_sniff(const unsigned short* __restrict__ w,
                            unsigned int* __restrict__ dt) {
  __shared__ int red[256];
  const int tid = threadIdx.x;
  int cnt = 0;
#pragma unroll
  for (int i = 0; i < 4; i++) {
    unsigned short h = w[tid * 4 + i];
    unsigned e = (h >> 7) & 0xFF;
    if (h == 0 || (e >= 100 && e <= 123)) cnt++;
  }
  red[tid] = cnt;
  __syncthreads();
  for (int s = 128; s > 0; s >>= 1) {
    if (tid < s) red[tid] += red[tid + s];
    __syncthreads();
  }
  if (tid == 0) dt[0] = (red[0] >= 922) ? 1u : 0u;   // 90% of 1024
}

// =====================================================================
// Phase A (unchanged): x_proj[tl][g][b] = x[b][t0+tl][:] . W_ih[g][:] + bias
// =====================================================================
__global__ __launch_bounds__(256) void xproj_gemm(
    const void* __restrict__ x, const void* __restrict__ Wih,
    const void* __restrict__ bih, const void* __restrict__ bhh,
    unsigned short* __restrict__ xp, int t0,
    const unsigned int* __restrict__ dt)
{
  __shared__ char smem[32768];
  __shared__ float bias_s[128];
  unsigned short* As = (unsigned short*)smem;            // [128][40]
  unsigned short* Bs = (unsigned short*)(smem + 10240);

  const bool isbf = (*dt != 0);

  const int bid = blockIdx.x;
  const int panel = bid >> 9;
  const int within = bid & 511;
  const int nt = within & 31;
  const int mt = (panel << 4) + (within >> 5);
  const int m0 = mt * 128;
  const int n0 = nt * 128;
  const int tl0 = m0 >> 5;

  const int tid = threadIdx.x;
  if (tid < 128) {
    bias_s[tid] = isbf
        ? bf2f(((const unsigned short*)bih)[n0 + tid]) +
          bf2f(((const unsigned short*)bhh)[n0 + tid])
        : ((const float*)bih)[n0 + tid] + ((const float*)bhh)[n0 + tid];
  }

  const int w = tid >> 6, lane = tid & 63;
  const int quad = lane >> 4, lr = lane & 15;
  const int wm = (w & 1) * 64, wn = (w >> 1) * 64;

  float4v acc[4][4];
#pragma unroll
  for (int i = 0; i < 4; i++)
#pragma unroll
    for (int j = 0; j < 4; j++) acc[i][j] = (float4v){0.f, 0.f, 0.f, 0.f};

  const int r = tid >> 1, half = tid & 1;
  const size_t aoff =
      ((size_t)(r & 31) * T_STEPS + (size_t)(t0 + tl0 + (r >> 5))) * HID + half * 16;
  const size_t boff = (size_t)(n0 + r) * HID + half * 16;
  unsigned short* adst = As + r * 40 + half * 16;
  unsigned short* bdst = Bs + r * 40 + half * 16;

  for (int k0 = 0; k0 < HID; k0 += 32) {
    __syncthreads();
    if (isbf) {
      const unsigned short* a16 = (const unsigned short*)x + aoff + k0;
      const unsigned short* b16 = (const unsigned short*)Wih + boff + k0;
      *(short8*)(adst)     = *(const short8*)(a16);
      *(short8*)(adst + 8) = *(const short8*)(a16 + 8);
      *(short8*)(bdst)     = *(const short8*)(b16);
      *(short8*)(bdst + 8) = *(const short8*)(b16 + 8);
    } else {
      const float4* af = (const float4*)((const float*)x + aoff + k0);
      const float4* bf = (const float4*)((const float*)Wih + boff + k0);
      float4 a0 = af[0], a1 = af[1], a2 = af[2], a3 = af[3];
      float4 b0 = bf[0], b1 = bf[1], b2 = bf[2], b3 = bf[3];
      *(short8*)(adst)     = pack8(a0, a1);
      *(short8*)(adst + 8) = pack8(a2, a3);
      *(short8*)(bdst)     = pack8(b0, b1);
      *(short8*)(bdst + 8) = pack8(b2, b3);
    }
    __syncthreads();
    short8 afr[4], bfr[4];
#pragma unroll
    for (int i = 0; i < 4; i++)
      afr[i] = *(const short8*)(As + (wm + i * 16 + lr) * 40 + quad * 8);
#pragma unroll
    for (int j = 0; j < 4; j++)
      bfr[j] = *(const short8*)(Bs + (wn + j * 16 + lr) * 40 + quad * 8);
#pragma unroll
    for (int i = 0; i < 4; i++)
#pragma unroll
      for (int j = 0; j < 4; j++)
        acc[i][j] = __builtin_amdgcn_mfma_f32_16x16x32_bf16(afr[i], bfr[j], acc[i][j], 0, 0, 0);
  }

  __syncthreads();
  unsigned short* ep = (unsigned short*)smem;
#pragma unroll
  for (int i = 0; i < 4; i++)
#pragma unroll
    for (int j = 0; j < 4; j++)
#pragma unroll
      for (int rr = 0; rr < 4; rr++) {
        int ml = wm + i * 16 + quad * 4 + rr;
        int nl = wn + j * 16 + lr;
        float v = acc[i][j][rr] + bias_s[nl];
        ep[(((ml >> 5) * 128) + nl) * 32 + (ml & 31)] = f2bf(v);
      }
  __syncthreads();
#pragma unroll
  for (int tl = 0; tl < 4; tl++) {
    const uint4* s4 = (const uint4*)(smem + tl * 8192);
    uint4* d4 = (uint4*)(xp + ((size_t)(tl0 + tl) * G4 + n0) * 32);
    for (int i = tid; i < 512; i += 256) d4[i] = s4[i];
  }
}

// =====================================================================
// Phase R: persistent LSTM recurrence. 64 WGs x 4 waves, K-SPLIT:
// wave w computes ALL 64 gate-cols of its WG over K-quarter [256w,+256).
// Its h-slice is the contiguous 16KB hbuf region of producer WGs
// [16w,16w+16) -> gathered DIRECTLY into A-fragment registers (16
// in-flight dwordx4, one vmcnt(0), sched_barrier). No LDS h-tile.
// Cross-wave K-reduction through gpart[4][64][36] (fp32) in LDS.
// Each wave polls only its own 16 producers (flags[64w..64w+64)).
// 2 barriers/step; publish after both barriers (overwrite-safe since
// the barrier point transitively confirms all 64 WGs reached step t).
// =====================================================================
__global__ __launch_bounds__(256, 1) void lstm_rec(
    const void* __restrict__ Whh,
    const unsigned short* __restrict__ xp,
    unsigned short* __restrict__ hbuf,   // 2 x 64KB WG-contiguous
    unsigned int* __restrict__ flags,    // NWG*4, global-step monotonic
    float* __restrict__ cstate,          // [32][1024] fp32, persists
    void* __restrict__ out,              // [h(32x1024) ; c(32x1024)]
    int t0, int tc,
    const unsigned int* __restrict__ dt)
{
  __shared__ float gpart[4][64][36];   // [wave][gate*16+col][batch(+pad)]

  const bool isbf = (*dt != 0);
  const int wg = blockIdx.x;
  const int tid = threadIdx.x;
  const int w = tid >> 6, lane = tid & 63;
  const int quad = lane >> 4, lr = lane & 15;

  // --- W_hh B-fragments: wave w = K-quarter [256w,+256), all 4 gates.
  //     bfrag[q*8+s]: lane(quad,lr) = W[q*1024 + wg*16 + lr][w*256+s*32+quad*8 ..+8]
  short8 bfrag[32];
#pragma unroll
  for (int q = 0; q < 4; q++) {
    const size_t grow = (size_t)q * HID + wg * 16 + lr;
    if (isbf) {
      const unsigned short* wrow = (const unsigned short*)Whh + grow * HID;
#pragma unroll
      for (int s = 0; s < 8; s++)
        bfrag[q * 8 + s] = *(const short8*)(wrow + w * 256 + s * 32 + quad * 8);
    } else {
      const float* wrow = (const float*)Whh + grow * HID;
#pragma unroll
      for (int s = 0; s < 8; s++) {
        float4 f0 = *(const float4*)(wrow + w * 256 + s * 32 + quad * 8);
        float4 f1 = *(const float4*)(wrow + w * 256 + s * 32 + quad * 8 + 4);
        bfrag[q * 8 + s] = pack8(f0, f1);
      }
    }
  }

  // cell ownership: (batch cb, local h-cols j0, j1)
  const int cb = 8 * w + (lane >> 3);
  const int ck = lane & 7;
  const int j0 = 2 * ck, j1 = j0 + 1;
  const int gc0 = wg * 16 + j0, gc1 = gc0 + 1;
  float cs0 = cstate[(size_t)cb * HID + gc0];
  float cs1 = cstate[(size_t)cb * HID + gc1];
  long budget = 50000000;

  // per-thread gather base (within one 64KB parity buffer):
  // addr(s,m) = w*16384 + s*2048 + (quad>>1)*1024 + m*512 + lr*32 + (quad&1)*16
  const int gbase_off = w * 16384 + (quad >> 1) * 1024 + lr * 32 + (quad & 1) * 16;

  for (int t = t0; t < t0 + tc; t++) {
    // ---- prefetch xp gate values (normal cached loads, issued early) ----
    const unsigned short* xpt = xp + (size_t)(t - t0) * (G4 * 32);
    unsigned short rx0 = xpt[(size_t)gc0 * 32 + cb];
    unsigned short rx1 = xpt[(size_t)(HID + gc0) * 32 + cb];
    unsigned short rx2 = xpt[(size_t)(2 * HID + gc0) * 32 + cb];
    unsigned short rx3 = xpt[(size_t)(3 * HID + gc0) * 32 + cb];
    unsigned short rx4 = xpt[(size_t)gc1 * 32 + cb];
    unsigned short rx5 = xpt[(size_t)(HID + gc1) * 32 + cb];
    unsigned short rx6 = xpt[(size_t)(2 * HID + gc1) * 32 + cb];
    unsigned short rx7 = xpt[(size_t)(3 * HID + gc1) * 32 + cb];

    // ---- wave w waits only for ITS 16 producers (64 contiguous flags) ----
    {
      const unsigned target = (unsigned)t;
      const unsigned int* fp = flags + 64 * w + lane;
      while (__hip_atomic_load(fp, __ATOMIC_RELAXED, __HIP_MEMORY_SCOPE_AGENT) < target) {
        if (--budget < 0) break;
        __builtin_amdgcn_s_sleep(1);
      }
    }

    // ---- register gather: 16 x dwordx4, all in flight, one drain ----
    short8 av[2][8];
    {
      const char* gb = (const char*)hbuf + (size_t)(t & 1) * 65536 + gbase_off;
#define GL(m, s) \
      asm volatile("global_load_dwordx4 %0, %1, off sc0 sc1" \
                   : "=v"(av[m][s]) : "v"(gb + (s) * 2048 + (m) * 512) : "memory")
      GL(0, 0); GL(1, 0); GL(0, 1); GL(1, 1);
      GL(0, 2); GL(1, 2); GL(0, 3); GL(1, 3);
      GL(0, 4); GL(1, 4); GL(0, 5); GL(1, 5);
      GL(0, 6); GL(1, 6); GL(0, 7); GL(1, 7);
#undef GL
      asm volatile("s_waitcnt vmcnt(0)" ::: "memory");
      __builtin_amdgcn_sched_barrier(0);
    }

    // ---- in-register MFMA: 64 MFMAs, 8 independent acc chains ----
    float4v acc[2][4];
#pragma unroll
    for (int m = 0; m < 2; m++)
#pragma unroll
      for (int q = 0; q < 4; q++) acc[m][q] = (float4v){0.f, 0.f, 0.f, 0.f};
#pragma unroll
    for (int s = 0; s < 8; s++) {
#pragma unroll
      for (int q = 0; q < 4; q++) {
        acc[0][q] = __builtin_amdgcn_mfma_f32_16x16x32_bf16(av[0][s], bfrag[q * 8 + s], acc[0][q], 0, 0, 0);
        acc[1][q] = __builtin_amdgcn_mfma_f32_16x16x32_bf16(av[1][s], bfrag[q * 8 + s], acc[1][q], 0, 0, 0);
      }
    }

    // ---- cross-wave K reduction via LDS ----
    __syncthreads();   // barrier 2: prev step's gpart reads complete
#pragma unroll
    for (int m = 0; m < 2; m++)
#pragma unroll
      for (int q = 0; q < 4; q++)
        *(float4v*)&gpart[w][q * 16 + lr][m * 16 + quad * 4] = acc[m][q];
    __syncthreads();   // barrier 1: all partials written (also: all 4 waves
                       // have polled -> all 64 WGs >= t -> publish is safe)

    // ---- cell: sum 4 partials per gate + xp, then LSTM elementwise ----
    {
      float gi0 = bf2f(rx0), gf0 = bf2f(rx1), gg0 = bf2f(rx2), go0 = bf2f(rx3);
      float gi1 = bf2f(rx4), gf1 = bf2f(rx5), gg1 = bf2f(rx6), go1 = bf2f(rx7);
#pragma unroll
      for (int p = 0; p < 4; p++) {
        gi0 += gpart[p][j0][cb];
        gf0 += gpart[p][16 + j0][cb];
        gg0 += gpart[p][32 + j0][cb];
        go0 += gpart[p][48 + j0][cb];
        gi1 += gpart[p][j1][cb];
        gf1 += gpart[p][16 + j1][cb];
        gg1 += gpart[p][32 + j1][cb];
        go1 += gpart[p][48 + j1][cb];
      }
      float si0 = 1.f / (1.f + __expf(-gi0));
      float sf0 = 1.f / (1.f + __expf(-gf0));
      float tg0 = tanhf(gg0);
      float so0 = 1.f / (1.f + __expf(-go0));
      cs0 = sf0 * cs0 + si0 * tg0;
      float hn0 = so0 * tanhf(cs0);

      float si1 = 1.f / (1.f + __expf(-gi1));
      float sf1 = 1.f / (1.f + __expf(-gf1));
      float tg1 = tanhf(gg1);
      float so1 = 1.f / (1.f + __expf(-go1));
      cs1 = sf1 * cs1 + si1 * tg1;
      float hn1 = so1 * tanhf(cs1);

      // publish packed (col j0 | col j1): byte = parity*65536 + wg*1024 + cb*32 + ck*4
      unsigned pk = (unsigned)f2bf(hn0) | ((unsigned)f2bf(hn1) << 16);
      unsigned int* hb32 = (unsigned int*)hbuf;
      const unsigned idx = (unsigned)(((t + 1) & 1) * 16384 + wg * 256 + cb * 8 + ck);
      __hip_atomic_store(hb32 + idx, pk, __ATOMIC_RELAXED, __HIP_MEMORY_SCOPE_AGENT);

      if (t == T_STEPS - 1) {
        if (isbf) {
          unsigned short* ob = (unsigned short*)out;
          ob[(size_t)cb * HID + gc0] = f2bf(hn0);
          ob[(size_t)cb * HID + gc1] = f2bf(hn1);
          ob[32768 + (size_t)cb * HID + gc0] = f2bf(cs0);
          ob[32768 + (size_t)cb * HID + gc1] = f2bf(cs1);
        } else {
          float* of = (float*)out;
          of[(size_t)cb * HID + gc0] = hn0;
          of[(size_t)cb * HID + gc1] = hn1;
          of[32768 + (size_t)cb * HID + gc0] = cs0;
          of[32768 + (size_t)cb * HID + gc1] = cs1;
        }
      }
    }
    // per-wave drain (covers publish stores AND this step's gather loads),
    // then per-wave flag release
    asm volatile("s_waitcnt vmcnt(0)" ::: "memory");
    if (lane == 0)
      __hip_atomic_store(&flags[wg * 4 + w], (unsigned)(t + 1), __ATOMIC_RELAXED,
                         __HIP_MEMORY_SCOPE_AGENT);
  }

  // persist c for the next chunk
  cstate[(size_t)cb * HID + gc0] = cs0;
  cstate[(size_t)cb * HID + gc1] = cs1;
}

extern "C" void kernel_launch(void* const* d_in, const int* in_sizes, int n_in,
                              void* d_out, int out_size, void* d_ws, size_t ws_size,
                              hipStream_t stream) {
  (void)in_sizes; (void)n_in; (void)out_size;
  const void* x   = d_in[0];
  const void* Wih = d_in[1];
  const void* Whh = d_in[2];
  const void* bih = d_in[3];
  const void* bhh = d_in[4];

  char* ws = (char*)d_ws;
  unsigned short* hbuf   = (unsigned short*)(ws + HBUF_OFF);
  unsigned int*   flags  = (unsigned int*)(ws + FLAG_OFF);
  unsigned int*   dt     = (unsigned int*)(ws + DT_OFF);
  float*          cstate = (float*)(ws + CST_OFF);
  unsigned short* xp     = (unsigned short*)(ws + XP_OFF);

  int tc = 2048;
  while (tc > 16 && XP_OFF + (size_t)tc * 262144ull > ws_size) tc >>= 1;

  hipMemsetAsync(ws, 0, CST_OFF + 131072, stream);

  hipLaunchKernelGGL(dtype_sniff, dim3(1), dim3(256), 0, stream,
                     (const unsigned short*)Wih, dt);

  for (int t0 = 0; t0 < T_STEPS; t0 += tc) {
    hipLaunchKernelGGL(xproj_gemm, dim3(tc * 8), dim3(256), 0, stream,
                       x, Wih, bih, bhh, xp, t0, dt);
    hipLaunchKernelGGL(lstm_rec, dim3(NWG), dim3(256), 0, stream,
                       Whh, xp, hbuf, flags, cstate, d_out, t0, tc, dt);
  }
}